// Round 3
// baseline (594.046 us; speedup 1.0000x reference)
//
#include <hip/hip_runtime.h>
#include <hip/hip_cooperative_groups.h>
#include <hip/hip_fp16.h>
#include <math.h>

namespace cg = cooperative_groups;

#define N_NODE 50000
#define D_FEAT 128
#define N_EDGE 625000
#define SIM_THRESH 0.1f
// fp16 sim error std ~3.5e-5; 5e-4 band is 14x margin, catches ~0.25% of edges
#define BAND_EPS 5e-4f

// ===========================================================================
// Single cooperative kernel: all phases, grid.sync() between them.
// Phase 2 is identical in structure to R2's edge_sim16 (the 54-us kernel),
// with the band fixup done INLINE (exact fp32 re-gather) instead of a
// separate kernel.
// ===========================================================================
__global__ __launch_bounds__(256, 4)
void fused_kernel(const int* __restrict__ row,
                  const int* __restrict__ col,
                  const float* __restrict__ ew,
                  const float* __restrict__ feat,
                  const float* __restrict__ gate,
                  float* __restrict__ out,
                  float* __restrict__ row_sum,
                  float* __restrict__ degree,
                  float* __restrict__ inv_nrm,
                  float* __restrict__ sim,
                  __half* __restrict__ fn16) {
    cg::grid_group grid = cg::this_grid();
    const int tid = blockIdx.x * blockDim.x + threadIdx.x;
    const int nthreads = gridDim.x * blockDim.x;

    // ---- Phase 0: zero accumulators (ws is poisoned 0xAA every call) ----
    for (int i = tid; i < N_NODE; i += nthreads) {
        row_sum[i] = 0.0f;
        degree[i] = 0.0f;
    }

    // ---- Phase 1: inv-norm + normalized fp16 features. 32 lanes/node ----
    {
        int lane = tid & 31;
        int ngroups = nthreads >> 5;
        for (int node = tid >> 5; node < N_NODE; node += ngroups) {
            float4 v = ((const float4*)(feat + (size_t)node * D_FEAT))[lane];
            float ss = v.x * v.x + v.y * v.y + v.z * v.z + v.w * v.w;
#pragma unroll
            for (int o = 16; o > 0; o >>= 1) ss += __shfl_down(ss, o, 32);
            ss = __shfl(ss, 0, 32);
            float inv = 1.0f / fmaxf(sqrtf(ss), 1e-12f);
            if (lane == 0) inv_nrm[node] = inv;
            __half2 h0 = __floats2half2_rn(v.x * inv, v.y * inv);
            __half2 h1 = __floats2half2_rn(v.z * inv, v.w * inv);
            uint2 p;
            p.x = *(unsigned int*)&h0;
            p.y = *(unsigned int*)&h1;
            ((uint2*)(fn16 + (size_t)node * D_FEAT))[lane] = p;  // 8B/lane coalesced
        }
    }

    grid.sync();
    __threadfence();  // belt-and-suspenders L1/L2 visibility across XCDs

    // ---- Phase 2: per-edge fp16 cosine sim, 16 lanes/edge, inline fixup ----
    {
        int lane = tid & 15;
        int ngroups = nthreads >> 4;
        for (int e = tid >> 4; e < N_EDGE; e += ngroups) {
            int r = row[e];
            int c = col[e];
            float4 a = ((const float4*)(fn16 + (size_t)r * D_FEAT))[lane];
            float4 b = ((const float4*)(fn16 + (size_t)c * D_FEAT))[lane];
            const __half2* ah = (const __half2*)&a;
            const __half2* bh = (const __half2*)&b;
            float d = 0.0f;
#pragma unroll
            for (int i = 0; i < 4; i++) {
                float2 af = __half22float2(ah[i]);
                float2 bf = __half22float2(bh[i]);
                d = fmaf(af.x, bf.x, d);
                d = fmaf(af.y, bf.y, d);
            }
#pragma unroll
            for (int o = 8; o > 0; o >>= 1) d += __shfl_down(d, o, 16);
            d = __shfl(d, 0, 16);  // broadcast; branch below is group-uniform
            if (fabsf(d - SIM_THRESH) < BAND_EPS) {
                // exact fp32 recompute (rare: ~0.25% of edges)
                const float4* fr = (const float4*)(feat + (size_t)r * D_FEAT);
                const float4* fc = (const float4*)(feat + (size_t)c * D_FEAT);
                float4 a0 = fr[lane], a1 = fr[lane + 16];
                float4 b0 = fc[lane], b1 = fc[lane + 16];
                float dd = a0.x * b0.x + a0.y * b0.y + a0.z * b0.z + a0.w * b0.w
                         + a1.x * b1.x + a1.y * b1.y + a1.z * b1.z + a1.w * b1.w;
#pragma unroll
                for (int o = 8; o > 0; o >>= 1) dd += __shfl_down(dd, o, 16);
                dd = __shfl(dd, 0, 16);
                d = dd * inv_nrm[r] * inv_nrm[c];
            }
            float s = (d < SIM_THRESH) ? 0.0f : d;
            if (lane == 0) {
                sim[e] = s;
                if (s != 0.0f) {
                    atomicAdd(&row_sum[r], s);
                    atomicAdd(&degree[r], 1.0f);
                }
            }
        }
    }

    grid.sync();
    __threadfence();

    // ---- Phase 3: epilogue, 1 thread/edge ----
    float gv = gate[0];
    for (int e = tid; e < N_EDGE; e += nthreads) {
        int r = row[e];
        float rs = row_sum[r];
        float denom = (rs > 0.0f) ? rs : 1.0f;
        float att = sim[e] / denom;
        if (r == col[e]) att += 1.0f / (degree[r] + 1.0f);
        att = expf(att);
        float o = gv * ew[e] + (1.0f - gv) * att;
        out[e] = fmaxf(o, 0.0f);
    }
}

// ===========================================================================
// Fallback (non-cooperative) path: R2 structure with inline band fixup.
// ===========================================================================
__global__ void prep_kernel(const float* __restrict__ feat,
                            float* __restrict__ inv_nrm,
                            __half* __restrict__ fn16,
                            float* __restrict__ row_sum,
                            float* __restrict__ degree) {
    int g = blockIdx.x * blockDim.x + threadIdx.x;
    if (g < N_NODE) { row_sum[g] = 0.0f; degree[g] = 0.0f; }
    int node = g >> 5;
    int lane = g & 31;
    if (node >= N_NODE) return;
    float4 v = ((const float4*)(feat + (size_t)node * D_FEAT))[lane];
    float ss = v.x * v.x + v.y * v.y + v.z * v.z + v.w * v.w;
#pragma unroll
    for (int o = 16; o > 0; o >>= 1) ss += __shfl_down(ss, o, 32);
    ss = __shfl(ss, 0, 32);
    float inv = 1.0f / fmaxf(sqrtf(ss), 1e-12f);
    if (lane == 0) inv_nrm[node] = inv;
    __half2 h0 = __floats2half2_rn(v.x * inv, v.y * inv);
    __half2 h1 = __floats2half2_rn(v.z * inv, v.w * inv);
    uint2 p;
    p.x = *(unsigned int*)&h0;
    p.y = *(unsigned int*)&h1;
    ((uint2*)(fn16 + (size_t)node * D_FEAT))[lane] = p;
}

__global__ void edge_sim16_kernel(const int* __restrict__ row,
                                  const int* __restrict__ col,
                                  const float* __restrict__ feat,
                                  const float* __restrict__ inv_nrm,
                                  const __half* __restrict__ fn16,
                                  float* __restrict__ sim_out,
                                  float* __restrict__ row_sum,
                                  float* __restrict__ degree) {
    int g = blockIdx.x * blockDim.x + threadIdx.x;
    int edge = g >> 4;
    int lane = g & 15;
    if (edge >= N_EDGE) return;
    int r = row[edge];
    int c = col[edge];
    float4 a = ((const float4*)(fn16 + (size_t)r * D_FEAT))[lane];
    float4 b = ((const float4*)(fn16 + (size_t)c * D_FEAT))[lane];
    const __half2* ah = (const __half2*)&a;
    const __half2* bh = (const __half2*)&b;
    float d = 0.0f;
#pragma unroll
    for (int i = 0; i < 4; i++) {
        float2 af = __half22float2(ah[i]);
        float2 bf = __half22float2(bh[i]);
        d = fmaf(af.x, bf.x, d);
        d = fmaf(af.y, bf.y, d);
    }
#pragma unroll
    for (int o = 8; o > 0; o >>= 1) d += __shfl_down(d, o, 16);
    d = __shfl(d, 0, 16);
    if (fabsf(d - SIM_THRESH) < BAND_EPS) {
        const float4* fr = (const float4*)(feat + (size_t)r * D_FEAT);
        const float4* fc = (const float4*)(feat + (size_t)c * D_FEAT);
        float4 a0 = fr[lane], a1 = fr[lane + 16];
        float4 b0 = fc[lane], b1 = fc[lane + 16];
        float dd = a0.x * b0.x + a0.y * b0.y + a0.z * b0.z + a0.w * b0.w
                 + a1.x * b1.x + a1.y * b1.y + a1.z * b1.z + a1.w * b1.w;
#pragma unroll
        for (int o = 8; o > 0; o >>= 1) dd += __shfl_down(dd, o, 16);
        dd = __shfl(dd, 0, 16);
        d = dd * inv_nrm[r] * inv_nrm[c];
    }
    float s = (d < SIM_THRESH) ? 0.0f : d;
    if (lane == 0) {
        sim_out[edge] = s;
        if (s != 0.0f) {
            atomicAdd(&row_sum[r], s);
            atomicAdd(&degree[r], 1.0f);
        }
    }
}

__global__ void edge_out_kernel(const int* __restrict__ row,
                                const int* __restrict__ col,
                                const float* __restrict__ sim,
                                const float* __restrict__ row_sum,
                                const float* __restrict__ degree,
                                const float* __restrict__ ew,
                                const float* __restrict__ gate,
                                float* __restrict__ out) {
    int e = blockIdx.x * blockDim.x + threadIdx.x;
    if (e >= N_EDGE) return;
    int r = row[e];
    float rs = row_sum[r];
    float denom = (rs > 0.0f) ? rs : 1.0f;
    float att = sim[e] / denom;
    if (r == col[e]) att += 1.0f / (degree[r] + 1.0f);
    att = expf(att);
    float gv = gate[0];
    float o = gv * ew[e] + (1.0f - gv) * att;
    out[e] = fmaxf(o, 0.0f);
}

// ===========================================================================
// Launch
// ===========================================================================
extern "C" void kernel_launch(void* const* d_in, const int* in_sizes, int n_in,
                              void* d_out, int out_size, void* d_ws, size_t ws_size,
                              hipStream_t stream) {
    const int*   edge_index = (const int*)d_in[0];   // [2, E]: row then col
    const float* ew         = (const float*)d_in[1];
    const float* feat       = (const float*)d_in[2];
    const float* gate       = (const float*)d_in[3];
    float*       out        = (float*)d_out;

    const int* row = edge_index;
    const int* col = edge_index + N_EDGE;

    // ws layout: row_sum[N] | degree[N] | inv_nrm[N] | sim[E] | fn16[N*128 halves]
    float* row_sum = (float*)d_ws;
    float* degree  = row_sum + N_NODE;
    float* inv_nrm = degree + N_NODE;
    float* sim     = inv_nrm + N_NODE;
    __half* fn16   = (__half*)(sim + N_EDGE);

    const int block = 256;

    // Cooperative-launch sizing (host-only queries: capture-safe, and their
    // CPU cost is paid once at graph-capture time, not per replay).
    int dev = 0;
    hipGetDevice(&dev);
    int num_cu = 0;
    hipDeviceGetAttribute(&num_cu, hipDeviceAttributeMultiprocessorCount, dev);
    int blocks_per_cu = 0;
    hipOccupancyMaxActiveBlocksPerMultiprocessor(&blocks_per_cu,
                                                 (const void*)fused_kernel,
                                                 block, 0);
    bool coop_ok = (num_cu > 0 && blocks_per_cu > 0);
    if (coop_ok) {
        int G = num_cu * blocks_per_cu;
        if (G > 4096) G = 4096;
        void* args[] = {
            (void*)&row, (void*)&col, (void*)&ew, (void*)&feat, (void*)&gate,
            (void*)&out, (void*)&row_sum, (void*)&degree, (void*)&inv_nrm,
            (void*)&sim, (void*)&fn16
        };
        hipError_t err = hipLaunchCooperativeKernel((void*)fused_kernel,
                                                    dim3(G), dim3(block),
                                                    args, 0, stream);
        if (err == hipSuccess) return;
    }

    // ---- fallback: 3-kernel path ----
    {
        long long threads = (long long)N_NODE * 32;
        prep_kernel<<<(int)((threads + block - 1) / block), block, 0, stream>>>(
            feat, inv_nrm, fn16, row_sum, degree);
    }
    {
        long long threads = (long long)N_EDGE * 16;
        edge_sim16_kernel<<<(int)((threads + block - 1) / block), block, 0, stream>>>(
            row, col, feat, inv_nrm, fn16, sim, row_sum, degree);
    }
    edge_out_kernel<<<(N_EDGE + block - 1) / block, block, 0, stream>>>(
        row, col, sim, row_sum, degree, ew, gate, out);
}

// Round 4
// 134.576 us; speedup vs baseline: 4.4142x; 4.4142x over previous
//
#include <hip/hip_runtime.h>
#include <hip/hip_fp16.h>
#include <math.h>

#define N_NODE 50000
#define D_FEAT 128
#define N_EDGE 625000
#define SIM_THRESH 0.1f
// fp8 screen: dot-error std ~3.4e-3, margin 0.03 is ~9 sigma.
#define SCREEN_LO 0.07f
// fp16 sim error std ~3.5e-5; 5e-4 band is ~14x margin.
#define BAND_EPS 5e-4f

typedef float v2f __attribute__((ext_vector_type(2)));

// ===========================================================================
// K1: per-node inv-norm; write normalized features as fp16 (value table) and
// fp8 e4m3 (screening table). Also zeroes row_sum/degree (ws poisoned 0xAA).
// 32 lanes per node.
// ===========================================================================
__global__ void prep_kernel(const float* __restrict__ feat,
                            float* __restrict__ inv_nrm,
                            __half* __restrict__ fn16,
                            unsigned int* __restrict__ fp8tab,  // 32 uints/row
                            float* __restrict__ row_sum,
                            float* __restrict__ degree) {
    int g = blockIdx.x * blockDim.x + threadIdx.x;
    if (g < N_NODE) { row_sum[g] = 0.0f; degree[g] = 0.0f; }
    int node = g >> 5;
    int lane = g & 31;
    if (node >= N_NODE) return;
    float4 v = ((const float4*)(feat + (size_t)node * D_FEAT))[lane];
    float ss = v.x * v.x + v.y * v.y + v.z * v.z + v.w * v.w;
#pragma unroll
    for (int o = 16; o > 0; o >>= 1) ss += __shfl_down(ss, o, 32);
    ss = __shfl(ss, 0, 32);
    float inv = 1.0f / fmaxf(sqrtf(ss), 1e-12f);
    if (lane == 0) inv_nrm[node] = inv;
    float x0 = v.x * inv, x1 = v.y * inv, x2 = v.z * inv, x3 = v.w * inv;
    // fp16 value table: 8 B/lane, coalesced
    __half2 h0 = __floats2half2_rn(x0, x1);
    __half2 h1 = __floats2half2_rn(x2, x3);
    uint2 p;
    p.x = *(unsigned int*)&h0;
    p.y = *(unsigned int*)&h1;
    ((uint2*)(fn16 + (size_t)node * D_FEAT))[lane] = p;
    // fp8 screening table: 4 B/lane, coalesced
    int w = __builtin_amdgcn_cvt_pk_fp8_f32(x0, x1, 0, false);
    w = __builtin_amdgcn_cvt_pk_fp8_f32(x2, x3, w, true);
    fp8tab[(size_t)node * 32 + lane] = (unsigned int)w;
}

// ===========================================================================
// K2: per-edge sim. 16 lanes/edge. Three-tier precision:
//   fp8 screen (all edges)  ->  fp16 value (sim8 > 0.07, ~21%)
//                           ->  fp32 exact (|sim16-0.1| < 5e-4, ~0.25%)
// ===========================================================================
__global__ void edge_sim8_kernel(const int* __restrict__ row,
                                 const int* __restrict__ col,
                                 const float* __restrict__ feat,
                                 const float* __restrict__ inv_nrm,
                                 const __half* __restrict__ fn16,
                                 const unsigned int* __restrict__ fp8tab,
                                 float* __restrict__ sim_out,
                                 float* __restrict__ row_sum,
                                 float* __restrict__ degree) {
    int g = blockIdx.x * blockDim.x + threadIdx.x;
    int edge = g >> 4;
    int lane = g & 15;
    if (edge >= N_EDGE) return;
    int r = row[edge];
    int c = col[edge];

    // --- tier 1: fp8 screen (8 B/lane per endpoint) ---
    uint2 aw = ((const uint2*)(fp8tab + (size_t)r * 32))[lane];
    uint2 bw = ((const uint2*)(fp8tab + (size_t)c * 32))[lane];
    v2f a01 = __builtin_amdgcn_cvt_pk_f32_fp8((int)aw.x, false);
    v2f a23 = __builtin_amdgcn_cvt_pk_f32_fp8((int)aw.x, true);
    v2f a45 = __builtin_amdgcn_cvt_pk_f32_fp8((int)aw.y, false);
    v2f a67 = __builtin_amdgcn_cvt_pk_f32_fp8((int)aw.y, true);
    v2f b01 = __builtin_amdgcn_cvt_pk_f32_fp8((int)bw.x, false);
    v2f b23 = __builtin_amdgcn_cvt_pk_f32_fp8((int)bw.x, true);
    v2f b45 = __builtin_amdgcn_cvt_pk_f32_fp8((int)bw.y, false);
    v2f b67 = __builtin_amdgcn_cvt_pk_f32_fp8((int)bw.y, true);
    float d = 0.0f;
    d = fmaf(a01.x, b01.x, d); d = fmaf(a01.y, b01.y, d);
    d = fmaf(a23.x, b23.x, d); d = fmaf(a23.y, b23.y, d);
    d = fmaf(a45.x, b45.x, d); d = fmaf(a45.y, b45.y, d);
    d = fmaf(a67.x, b67.x, d); d = fmaf(a67.y, b67.y, d);
#pragma unroll
    for (int o = 8; o > 0; o >>= 1) d += __shfl_down(d, o, 16);
    d = __shfl(d, 0, 16);  // broadcast -> group-uniform branch

    float s = 0.0f;
    if (d > SCREEN_LO) {
        // --- tier 2: fp16 value (16 B/lane per endpoint) ---
        float4 a = ((const float4*)(fn16 + (size_t)r * D_FEAT))[lane];
        float4 b = ((const float4*)(fn16 + (size_t)c * D_FEAT))[lane];
        const __half2* ah = (const __half2*)&a;
        const __half2* bh = (const __half2*)&b;
        float dh = 0.0f;
#pragma unroll
        for (int i = 0; i < 4; i++) {
            float2 af = __half22float2(ah[i]);
            float2 bf = __half22float2(bh[i]);
            dh = fmaf(af.x, bf.x, dh);
            dh = fmaf(af.y, bf.y, dh);
        }
#pragma unroll
        for (int o = 8; o > 0; o >>= 1) dh += __shfl_down(dh, o, 16);
        dh = __shfl(dh, 0, 16);
        if (fabsf(dh - SIM_THRESH) < BAND_EPS) {
            // --- tier 3: exact fp32 (rare) ---
            const float4* fr = (const float4*)(feat + (size_t)r * D_FEAT);
            const float4* fc = (const float4*)(feat + (size_t)c * D_FEAT);
            float4 a0 = fr[lane], a1 = fr[lane + 16];
            float4 b0 = fc[lane], b1 = fc[lane + 16];
            float dd = a0.x * b0.x + a0.y * b0.y + a0.z * b0.z + a0.w * b0.w
                     + a1.x * b1.x + a1.y * b1.y + a1.z * b1.z + a1.w * b1.w;
#pragma unroll
            for (int o = 8; o > 0; o >>= 1) dd += __shfl_down(dd, o, 16);
            dd = __shfl(dd, 0, 16);
            dh = dd * inv_nrm[r] * inv_nrm[c];
        }
        s = (dh < SIM_THRESH) ? 0.0f : dh;
    }
    if (lane == 0) {
        sim_out[edge] = s;
        if (s != 0.0f) {
            atomicAdd(&row_sum[r], s);
            atomicAdd(&degree[r], 1.0f);
        }
    }
}

// ===========================================================================
// K3: epilogue — normalize, diagonal lam, exp, gate blend, clamp.
// ===========================================================================
__global__ void edge_out_kernel(const int* __restrict__ row,
                                const int* __restrict__ col,
                                const float* __restrict__ sim,
                                const float* __restrict__ row_sum,
                                const float* __restrict__ degree,
                                const float* __restrict__ ew,
                                const float* __restrict__ gate,
                                float* __restrict__ out) {
    int e = blockIdx.x * blockDim.x + threadIdx.x;
    if (e >= N_EDGE) return;
    int r = row[e];
    float rs = row_sum[r];
    float denom = (rs > 0.0f) ? rs : 1.0f;
    float att = sim[e] / denom;
    if (r == col[e]) att += 1.0f / (degree[r] + 1.0f);
    att = expf(att);
    float gv = gate[0];
    float o = gv * ew[e] + (1.0f - gv) * att;
    out[e] = fmaxf(o, 0.0f);
}

// ===========================================================================
// Fallback (pure fp32, small-ws) path.
// ===========================================================================
__global__ void inv_norm_kernel(const float* __restrict__ feat,
                                float* __restrict__ inv_nrm,
                                float* __restrict__ row_sum,
                                float* __restrict__ degree) {
    int g = blockIdx.x * blockDim.x + threadIdx.x;
    if (g < N_NODE) { row_sum[g] = 0.0f; degree[g] = 0.0f; }
    int node = g >> 5;
    int lane = g & 31;
    if (node >= N_NODE) return;
    float4 v = ((const float4*)(feat + (size_t)node * D_FEAT))[lane];
    float ss = v.x * v.x + v.y * v.y + v.z * v.z + v.w * v.w;
#pragma unroll
    for (int o = 16; o > 0; o >>= 1) ss += __shfl_down(ss, o, 32);
    if (lane == 0) inv_nrm[node] = 1.0f / fmaxf(sqrtf(ss), 1e-12f);
}

__global__ void edge_sim_kernel(const int* __restrict__ row,
                                const int* __restrict__ col,
                                const float* __restrict__ feat,
                                const float* __restrict__ inv_nrm,
                                float* __restrict__ sim_out,
                                float* __restrict__ row_sum,
                                float* __restrict__ degree) {
    int g = blockIdx.x * blockDim.x + threadIdx.x;
    int edge = g >> 5;
    int lane = g & 31;
    if (edge >= N_EDGE) return;
    int r = row[edge];
    int c = col[edge];
    float4 a = ((const float4*)(feat + (size_t)r * D_FEAT))[lane];
    float4 b = ((const float4*)(feat + (size_t)c * D_FEAT))[lane];
    float d = a.x * b.x + a.y * b.y + a.z * b.z + a.w * b.w;
#pragma unroll
    for (int o = 16; o > 0; o >>= 1) d += __shfl_down(d, o, 32);
    if (lane == 0) {
        float s = d * inv_nrm[r] * inv_nrm[c];
        if (s < SIM_THRESH) s = 0.0f;
        sim_out[edge] = s;
        if (s != 0.0f) {
            atomicAdd(&row_sum[r], s);
            atomicAdd(&degree[r], 1.0f);
        }
    }
}

// ===========================================================================
// Launch — 3 dispatches, no cooperative launch (grid.sync costs ~600 us on
// MI355X across XCDs; see R3 post-mortem).
// ===========================================================================
extern "C" void kernel_launch(void* const* d_in, const int* in_sizes, int n_in,
                              void* d_out, int out_size, void* d_ws, size_t ws_size,
                              hipStream_t stream) {
    const int*   edge_index = (const int*)d_in[0];   // [2, E]: row then col
    const float* ew         = (const float*)d_in[1];
    const float* feat       = (const float*)d_in[2];
    const float* gate       = (const float*)d_in[3];
    float*       out        = (float*)d_out;

    const int* row = edge_index;
    const int* col = edge_index + N_EDGE;

    // ws layout: row_sum[N] | degree[N] | inv_nrm[N] | sim[E]
    //            | fn16[N*128 halves] | fp8tab[N*32 uints]
    float* row_sum = (float*)d_ws;
    float* degree  = row_sum + N_NODE;
    float* inv_nrm = degree + N_NODE;
    float* sim     = inv_nrm + N_NODE;
    __half* fn16   = (__half*)(sim + N_EDGE);
    unsigned int* fp8tab = (unsigned int*)(fn16 + (size_t)N_NODE * D_FEAT);

    size_t need = (size_t)(3 * N_NODE + N_EDGE) * 4
                + (size_t)N_NODE * D_FEAT * 2
                + (size_t)N_NODE * D_FEAT;

    const int block = 256;

    if (ws_size >= need) {
        {
            long long threads = (long long)N_NODE * 32;
            prep_kernel<<<(int)((threads + block - 1) / block), block, 0, stream>>>(
                feat, inv_nrm, fn16, fp8tab, row_sum, degree);
        }
        {
            long long threads = (long long)N_EDGE * 16;
            edge_sim8_kernel<<<(int)((threads + block - 1) / block), block, 0, stream>>>(
                row, col, feat, inv_nrm, fn16, fp8tab, sim, row_sum, degree);
        }
        edge_out_kernel<<<(N_EDGE + block - 1) / block, block, 0, stream>>>(
            row, col, sim, row_sum, degree, ew, gate, out);
    } else {
        {
            long long threads = (long long)N_NODE * 32;
            inv_norm_kernel<<<(int)((threads + block - 1) / block), block, 0, stream>>>(
                feat, inv_nrm, row_sum, degree);
        }
        {
            long long threads = (long long)N_EDGE * 32;
            edge_sim_kernel<<<(int)((threads + block - 1) / block), block, 0, stream>>>(
                row, col, feat, inv_nrm, sim, row_sum, degree);
        }
        edge_out_kernel<<<(N_EDGE + block - 1) / block, block, 0, stream>>>(
            row, col, sim, row_sum, degree, ew, gate, out);
    }
}